// Round 11
// baseline (1343.115 us; speedup 1.0000x reference)
//
#include <hip/hip_runtime.h>
#include <hip/hip_cooperative_groups.h>

namespace cg = cooperative_groups;

#define N_NODES 100000
#define N_EDGES 1000000
#define D 64

typedef float f2v __attribute__((ext_vector_type(2)));

__device__ __forceinline__ unsigned int bf16_rne(float f) {
    unsigned int b = __float_as_uint(f);
    return (b + 0x7FFFu + ((b >> 16) & 1u)) >> 16;
}
__device__ __forceinline__ float bf16_lo(unsigned int v) { return __uint_as_float(v << 16); }
__device__ __forceinline__ float bf16_hi(unsigned int v) { return __uint_as_float(v & 0xFFFF0000u); }
__device__ __forceinline__ float bf16_f(unsigned short u) {
    return __uint_as_float(((unsigned int)u) << 16);
}

// Fused persistent pipeline: prep -> grid.sync -> pk-atomic scatter -> grid.sync -> GEMM.
// LDS = 64*64*4 (Wl, unpadded: reads are lane-consecutive -> conflict-free) +
//       4*4*64*4 (hl) = 20 KB exactly -> 8 blocks/CU.
__global__ __launch_bounds__(256, 8) void gine_fused(
        const float* __restrict__ x, const int* __restrict__ ei,
        const float* __restrict__ ea, const float* __restrict__ W,
        const float* __restrict__ bias, const float* __restrict__ eps,
        unsigned short* __restrict__ xh, unsigned short* __restrict__ outb,
        float* __restrict__ out) {
    cg::grid_group grid = cg::this_grid();
    __shared__ float Wl[D][D];                  // Wl[dd][o] = W[o][dd]
    __shared__ __align__(16) float hl[4][4][D];

    int tid = threadIdx.x;
    int gid0 = blockIdx.x * 256 + tid;
    int tot = gridDim.x * 256;
    float s = 1.0f + eps[0];

    // ---- phase 1: xh = bf16(x); outb = bf16((1+eps)x)  (base term pre-folded) ----
    for (int i = gid0; i < N_NODES * D / 8; i += tot) {
        float4 q0 = ((const float4*)x)[i * 2 + 0];
        float4 q1 = ((const float4*)x)[i * 2 + 1];
        uint4 a;
        a.x = bf16_rne(q0.x) | (bf16_rne(q0.y) << 16);
        a.y = bf16_rne(q0.z) | (bf16_rne(q0.w) << 16);
        a.z = bf16_rne(q1.x) | (bf16_rne(q1.y) << 16);
        a.w = bf16_rne(q1.z) | (bf16_rne(q1.w) << 16);
        ((uint4*)xh)[i] = a;
        uint4 o;
        o.x = bf16_rne(s * q0.x) | (bf16_rne(s * q0.y) << 16);
        o.y = bf16_rne(s * q0.z) | (bf16_rne(s * q0.w) << 16);
        o.z = bf16_rne(s * q1.x) | (bf16_rne(s * q1.y) << 16);
        o.w = bf16_rne(s * q1.z) | (bf16_rne(s * q1.w) << 16);
        ((uint4*)outb)[i] = o;
    }
    __threadfence();                 // agent release: writeback L2 so memory-side
    grid.sync();                     // atomics in phase 2 RMW the fresh values

    // ---- phase 2: streaming edge scatter, packed-bf16 atomics (proven r9 form) ----
    for (int task = gid0; task < N_EDGES * 32; task += tot) {
        int w = task >> 5;           // edge (uniform per 32-lane half-wave)
        int s2 = task & 31;          // feature pair
        int src = ei[w];
        int dst = ei[N_EDGES + w];
        f2v ev = __builtin_nontemporal_load((const f2v*)(ea + (long long)w * D) + s2);
        unsigned int xv = *((const unsigned int*)(xh + (long long)src * D) + s2);
        float mx = fmaxf(ev.x + bf16_lo(xv), 0.0f);
        float my = fmaxf(ev.y + bf16_hi(xv), 0.0f);
        unsigned int pk = bf16_rne(mx) | (bf16_rne(my) << 16);
        void* addr = (void*)(outb + (long long)dst * D + 2 * s2);
        asm volatile("global_atomic_pk_add_bf16 %0, %1, off" :: "v"(addr), "v"(pk) : "memory");
    }
    asm volatile("s_waitcnt vmcnt(0)" ::: "memory");   // drain own atomics
    __threadfence();                 // acquire side invalidates L2 for phase 3
    grid.sync();

    // ---- phase 3: out = relu(outb @ W^T + b) ----
    for (int i = tid; i < D * D; i += 256) {
        Wl[i & 63][i >> 6] = W[i];   // transpose-stage (once; conflict only here)
    }
    __syncthreads();
    int o = tid & 63;
    int wid = __builtin_amdgcn_readfirstlane(tid >> 6);
    float bv = bias[o];
    for (int g = blockIdx.x; g < (N_NODES + 63) / 64; g += gridDim.x) {
        int base = g * 64 + wid * 16;
        for (int t = 0; t < 4; ++t) {
            int r0 = base + t * 4;
            #pragma unroll
            for (int r = 0; r < 4; ++r) {
                int rr = r0 + r;
                float hv = 0.0f;
                if (rr < N_NODES) hv = bf16_f(outb[(long long)rr * D + o]);
                hl[wid][r][o] = hv;            // wave-private: no barrier needed
            }
            float a0 = bv, a1 = bv, a2 = bv, a3 = bv;
            #pragma unroll
            for (int dq = 0; dq < 16; ++dq) {
                float4 h0 = *(const float4*)&hl[wid][0][dq * 4];  // broadcast
                float4 h1 = *(const float4*)&hl[wid][1][dq * 4];
                float4 h2 = *(const float4*)&hl[wid][2][dq * 4];
                float4 h3 = *(const float4*)&hl[wid][3][dq * 4];
                float w0 = Wl[dq * 4 + 0][o];  // lane-consecutive: conflict-free
                float w1 = Wl[dq * 4 + 1][o];
                float w2 = Wl[dq * 4 + 2][o];
                float w3 = Wl[dq * 4 + 3][o];
                a0 = fmaf(h0.w, w3, fmaf(h0.z, w2, fmaf(h0.y, w1, fmaf(h0.x, w0, a0))));
                a1 = fmaf(h1.w, w3, fmaf(h1.z, w2, fmaf(h1.y, w1, fmaf(h1.x, w0, a1))));
                a2 = fmaf(h2.w, w3, fmaf(h2.z, w2, fmaf(h2.y, w1, fmaf(h2.x, w0, a2))));
                a3 = fmaf(h3.w, w3, fmaf(h3.z, w2, fmaf(h3.y, w1, fmaf(h3.x, w0, a3))));
            }
            if (r0 + 0 < N_NODES) out[(long long)(r0 + 0) * D + o] = fmaxf(a0, 0.0f);
            if (r0 + 1 < N_NODES) out[(long long)(r0 + 1) * D + o] = fmaxf(a1, 0.0f);
            if (r0 + 2 < N_NODES) out[(long long)(r0 + 2) * D + o] = fmaxf(a2, 0.0f);
            if (r0 + 3 < N_NODES) out[(long long)(r0 + 3) * D + o] = fmaxf(a3, 0.0f);
        }
    }
}

// ============ non-cooperative fallback: proven r10 3-kernel pipeline ============

__global__ __launch_bounds__(256) void gine_prep(const float* __restrict__ x,
                                                 const float* __restrict__ eps,
                                                 uint4* __restrict__ xh4,
                                                 uint4* __restrict__ ob4) {
    int i = blockIdx.x * 256 + threadIdx.x;
    float s = 1.0f + eps[0];
    if (i < N_NODES * D / 8) {
        float4 q0 = ((const float4*)x)[i * 2 + 0];
        float4 q1 = ((const float4*)x)[i * 2 + 1];
        uint4 a;
        a.x = bf16_rne(q0.x) | (bf16_rne(q0.y) << 16);
        a.y = bf16_rne(q0.z) | (bf16_rne(q0.w) << 16);
        a.z = bf16_rne(q1.x) | (bf16_rne(q1.y) << 16);
        a.w = bf16_rne(q1.z) | (bf16_rne(q1.w) << 16);
        xh4[i] = a;
        uint4 o;
        o.x = bf16_rne(s * q0.x) | (bf16_rne(s * q0.y) << 16);
        o.y = bf16_rne(s * q0.z) | (bf16_rne(s * q0.w) << 16);
        o.z = bf16_rne(s * q1.x) | (bf16_rne(s * q1.y) << 16);
        o.w = bf16_rne(s * q1.z) | (bf16_rne(s * q1.w) << 16);
        ob4[i] = o;
    }
}

__global__ __launch_bounds__(256) void gine_edges_pk(const unsigned short* __restrict__ xh,
                                                     const int* __restrict__ ei,
                                                     const float* __restrict__ ea,
                                                     unsigned short* __restrict__ outb) {
    int t = blockIdx.x * 256 + threadIdx.x;
    int w = t >> 5;
    int s2 = t & 31;
    if (w < N_EDGES) {
        int src = ei[w];
        int dst = ei[N_EDGES + w];
        f2v ev = __builtin_nontemporal_load((const f2v*)(ea + (long long)w * D) + s2);
        unsigned int xv = *((const unsigned int*)(xh + (long long)src * D) + s2);
        float mx = fmaxf(ev.x + bf16_lo(xv), 0.0f);
        float my = fmaxf(ev.y + bf16_hi(xv), 0.0f);
        unsigned int pk = bf16_rne(mx) | (bf16_rne(my) << 16);
        void* addr = (void*)(outb + (long long)dst * D + 2 * s2);
        asm volatile("global_atomic_pk_add_bf16 %0, %1, off" :: "v"(addr), "v"(pk) : "memory");
    }
    asm volatile("s_waitcnt vmcnt(0)" ::: "memory");
}

__global__ __launch_bounds__(256) void gine_lin(const unsigned short* __restrict__ outb,
                                                const float* __restrict__ W,
                                                const float* __restrict__ bias,
                                                float* __restrict__ out) {
    __shared__ float Wl[D][D];
    __shared__ __align__(16) float hl[4][4][D];
    int tid = threadIdx.x;
    for (int i = tid; i < D * D; i += 256) Wl[i & 63][i >> 6] = W[i];
    __syncthreads();
    int o = tid & 63;
    int wid = __builtin_amdgcn_readfirstlane(tid >> 6);
    float bv = bias[o];
    int base = blockIdx.x * 64 + wid * 16;
    for (int t = 0; t < 4; ++t) {
        int r0 = base + t * 4;
        #pragma unroll
        for (int r = 0; r < 4; ++r) {
            int rr = r0 + r;
            float hv = 0.0f;
            if (rr < N_NODES) hv = bf16_f(outb[(long long)rr * D + o]);
            hl[wid][r][o] = hv;
        }
        float a0 = bv, a1 = bv, a2 = bv, a3 = bv;
        #pragma unroll
        for (int dq = 0; dq < 16; ++dq) {
            float4 h0 = *(const float4*)&hl[wid][0][dq * 4];
            float4 h1 = *(const float4*)&hl[wid][1][dq * 4];
            float4 h2 = *(const float4*)&hl[wid][2][dq * 4];
            float4 h3 = *(const float4*)&hl[wid][3][dq * 4];
            float w0 = Wl[dq * 4 + 0][o];
            float w1 = Wl[dq * 4 + 1][o];
            float w2 = Wl[dq * 4 + 2][o];
            float w3 = Wl[dq * 4 + 3][o];
            a0 = fmaf(h0.w, w3, fmaf(h0.z, w2, fmaf(h0.y, w1, fmaf(h0.x, w0, a0))));
            a1 = fmaf(h1.w, w3, fmaf(h1.z, w2, fmaf(h1.y, w1, fmaf(h1.x, w0, a1))));
            a2 = fmaf(h2.w, w3, fmaf(h2.z, w2, fmaf(h2.y, w1, fmaf(h2.x, w0, a2))));
            a3 = fmaf(h3.w, w3, fmaf(h3.z, w2, fmaf(h3.y, w1, fmaf(h3.x, w0, a3))));
        }
        if (r0 + 0 < N_NODES) out[(long long)(r0 + 0) * D + o] = fmaxf(a0, 0.0f);
        if (r0 + 1 < N_NODES) out[(long long)(r0 + 1) * D + o] = fmaxf(a1, 0.0f);
        if (r0 + 2 < N_NODES) out[(long long)(r0 + 2) * D + o] = fmaxf(a2, 0.0f);
        if (r0 + 3 < N_NODES) out[(long long)(r0 + 3) * D + o] = fmaxf(a3, 0.0f);
    }
}

// fp32 atomic fallback (no ws)
__global__ __launch_bounds__(256) void gine_init(const float* __restrict__ x,
                                                 const float* __restrict__ eps,
                                                 float* __restrict__ out, int n4) {
    int i = blockIdx.x * blockDim.x + threadIdx.x;
    float s = 1.0f + eps[0];
    if (i < n4) {
        float4 v = ((const float4*)x)[i];
        v.x *= s; v.y *= s; v.z *= s; v.w *= s;
        ((float4*)out)[i] = v;
    }
}
__global__ __launch_bounds__(256) void gine_edges(const float* __restrict__ x,
                                                  const int* __restrict__ ei,
                                                  const float* __restrict__ ea,
                                                  float* __restrict__ out) {
    int e = blockIdx.x * (blockDim.x >> 6) + (threadIdx.x >> 6);
    int d = threadIdx.x & 63;
    if (e < N_EDGES) {
        int s = ei[e];
        int t = ei[N_EDGES + e];
        float m = fmaxf(x[(long long)s * D + d] + ea[(long long)e * D + d], 0.0f);
        atomicAdd(&out[(long long)t * D + d], m);
    }
}
__global__ __launch_bounds__(256) void gine_linear(float* __restrict__ h,
                                                   const float* __restrict__ W,
                                                   const float* __restrict__ b) {
    __shared__ float Wl[D][D + 1];
    __shared__ float bl[D];
    int tid = threadIdx.x;
    for (int i = tid; i < D * D; i += 256) Wl[i >> 6][i & 63] = W[i];
    if (tid < D) bl[tid] = b[tid];
    __syncthreads();
    int o = tid & 63;
    int row = blockIdx.x * 4 + (tid >> 6);
    if (row < N_NODES) {
        const float* hr = h + (long long)row * D;
        float acc = bl[o];
        #pragma unroll
        for (int d = 0; d < D; ++d) acc = fmaf(hr[d], Wl[o][d], acc);
        h[(long long)row * D + o] = fmaxf(acc, 0.0f);
    }
}

extern "C" void kernel_launch(void* const* d_in, const int* in_sizes, int n_in,
                              void* d_out, int out_size, void* d_ws, size_t ws_size,
                              hipStream_t stream) {
    const float* x   = (const float*)d_in[0];
    const int*   ei  = (const int*)d_in[1];   // int32 on device (harness narrows int64)
    const float* ea  = (const float*)d_in[2];
    const float* W   = (const float*)d_in[3];
    const float* b   = (const float*)d_in[4];
    const float* eps = (const float*)d_in[5];
    float* out = (float*)d_out;

    // ws layout: xh[N*D] bf16 | outb[N*D] bf16
    size_t need = (size_t)N_NODES * D * 2 * 2;
    if (ws_size >= need) {
        unsigned short* xh   = (unsigned short*)d_ws;
        unsigned short* outb = xh + (size_t)N_NODES * D;

        int dev = 0, coop = 0, nb = 0;
        hipGetDevice(&dev);
        hipDeviceGetAttribute(&coop, hipDeviceAttributeCooperativeLaunch, dev);
        bool done = false;
        if (coop &&
            hipOccupancyMaxActiveBlocksPerMultiprocessor(&nb, gine_fused, 256, 0) ==
                hipSuccess && nb > 0) {
            int ncu = 0;
            hipDeviceGetAttribute(&ncu, hipDeviceAttributeMultiprocessorCount, dev);
            if (ncu <= 0) ncu = 256;
            dim3 grid(nb * ncu), block(256);
            void* args[] = {(void*)&x, (void*)&ei, (void*)&ea, (void*)&W, (void*)&b,
                            (void*)&eps, (void*)&xh, (void*)&outb, (void*)&out};
            if (hipLaunchCooperativeKernel(gine_fused, grid, block, args, 0, stream) ==
                hipSuccess) {
                done = true;
            }
        }
        if (!done) {
            gine_prep<<<(N_NODES * D / 8 + 255) / 256, 256, 0, stream>>>(
                x, eps, (uint4*)xh, (uint4*)outb);
            gine_edges_pk<<<(N_EDGES * 32) / 256, 256, 0, stream>>>(xh, ei, ea, outb);
            gine_lin<<<(N_NODES + 63) / 64, 256, 0, stream>>>(outb, W, b, out);
        }
    } else {
        int n4 = (N_NODES * D) / 4;
        gine_init<<<(n4 + 255) / 256, 256, 0, stream>>>(x, eps, out, n4);
        gine_edges<<<(N_EDGES + 3) / 4, 256, 0, stream>>>(x, ei, ea, out);
        gine_linear<<<(N_NODES + 3) / 4, 256, 0, stream>>>(out, W, b);
    }
}

// Round 12
// 245.728 us; speedup vs baseline: 5.4659x; 5.4659x over previous
//
#include <hip/hip_runtime.h>

#define N_NODES 100000
#define N_EDGES 1000000
#define D 64

typedef float f2v __attribute__((ext_vector_type(2)));

__device__ __forceinline__ unsigned int bf16_rne(float f) {
    unsigned int b = __float_as_uint(f);
    return (b + 0x7FFFu + ((b >> 16) & 1u)) >> 16;
}
__device__ __forceinline__ float bf16_lo(unsigned int v) { return __uint_as_float(v << 16); }
__device__ __forceinline__ float bf16_hi(unsigned int v) { return __uint_as_float(v & 0xFFFF0000u); }
__device__ __forceinline__ float bf16_f(unsigned short u) {
    return __uint_as_float(((unsigned int)u) << 16);
}

// prep: xh = bf16(x); ob = bf16((1+eps)*x)  (GIN base folded into the agg buffer).
__global__ __launch_bounds__(256) void gine_prep(const float* __restrict__ x,
                                                 const float* __restrict__ eps,
                                                 uint4* __restrict__ xh4,
                                                 uint4* __restrict__ ob4) {
    int i = blockIdx.x * 256 + threadIdx.x;
    float s = 1.0f + eps[0];
    if (i < N_NODES * D / 8) {
        float4 q0 = ((const float4*)x)[i * 2 + 0];
        float4 q1 = ((const float4*)x)[i * 2 + 1];
        uint4 a;
        a.x = bf16_rne(q0.x) | (bf16_rne(q0.y) << 16);
        a.y = bf16_rne(q0.z) | (bf16_rne(q0.w) << 16);
        a.z = bf16_rne(q1.x) | (bf16_rne(q1.y) << 16);
        a.w = bf16_rne(q1.z) | (bf16_rne(q1.w) << 16);
        xh4[i] = a;
        uint4 o;
        o.x = bf16_rne(s * q0.x) | (bf16_rne(s * q0.y) << 16);
        o.y = bf16_rne(s * q0.z) | (bf16_rne(s * q0.w) << 16);
        o.z = bf16_rne(s * q1.x) | (bf16_rne(s * q1.y) << 16);
        o.w = bf16_rne(s * q1.z) | (bf16_rne(s * q1.w) << 16);
        ob4[i] = o;
    }
}

// Streaming edge scatter with packed-bf16 atomics.
// One edge per 32-lane half-wave; lane covers feature pair (2*s2, 2*s2+1).
// NEW: skip zero packets — post-relu pair == 0 with p~0.25; adding +0.0 is a
// no-op, and exec-masked lanes issue no fabric packet -> ~25% fewer atomics.
__global__ __launch_bounds__(256) void gine_edges_pk(const unsigned short* __restrict__ xh,
                                                     const int* __restrict__ ei,
                                                     const float* __restrict__ ea,
                                                     unsigned short* __restrict__ outb) {
    int t = blockIdx.x * 256 + threadIdx.x;
    int w = t >> 5;                // edge index (uniform per half-wave)
    int s2 = t & 31;               // feature-pair index
    if (w < N_EDGES) {
        int src = ei[w];               // broadcast load (same addr across half-wave)
        int dst = ei[N_EDGES + w];
        f2v ev = __builtin_nontemporal_load((const f2v*)(ea + (long long)w * D) + s2);
        unsigned int xv = *((const unsigned int*)(xh + (long long)src * D) + s2);
        float mx = fmaxf(ev.x + bf16_lo(xv), 0.0f);
        float my = fmaxf(ev.y + bf16_hi(xv), 0.0f);
        unsigned int pk = bf16_rne(mx) | (bf16_rne(my) << 16);
        if (pk != 0u) {
            void* addr = (void*)(outb + (long long)dst * D + 2 * s2);
            asm volatile("global_atomic_pk_add_bf16 %0, %1, off" :: "v"(addr), "v"(pk) : "memory");
        }
    }
    asm volatile("s_waitcnt vmcnt(0)" ::: "memory");   // drain atomics before endpgm
}

// lin: out = relu(ob @ W^T + b); ob already holds (1+eps)x + aggregate.
__global__ __launch_bounds__(256) void gine_lin(const unsigned short* __restrict__ outb,
                                                const float* __restrict__ W,
                                                const float* __restrict__ bias,
                                                float* __restrict__ out) {
    __shared__ float Wl[D][D + 1];             // Wl[dd][o] = W[o][dd]
    __shared__ __align__(16) float hl[4][4][D];
    int tid = threadIdx.x;
    for (int i = tid; i < D * D; i += 256) {
        int o = i >> 6, dd = i & 63;
        Wl[dd][o] = W[i];
    }
    __syncthreads();

    int o = tid & 63;
    int wid = __builtin_amdgcn_readfirstlane(threadIdx.x >> 6);
    float bv = bias[o];
    int base = blockIdx.x * 64 + wid * 16;

    for (int t = 0; t < 4; ++t) {
        int r0 = base + t * 4;
        #pragma unroll
        for (int r = 0; r < 4; ++r) {
            int rr = r0 + r;
            float hv = 0.0f;
            if (rr < N_NODES) hv = bf16_f(outb[(long long)rr * D + o]);
            hl[wid][r][o] = hv;                // wave-private: no barrier needed
        }
        float a0 = bv, a1 = bv, a2 = bv, a3 = bv;
        #pragma unroll
        for (int dq = 0; dq < 16; ++dq) {
            float4 h0 = *(const float4*)&hl[wid][0][dq * 4];
            float4 h1 = *(const float4*)&hl[wid][1][dq * 4];
            float4 h2 = *(const float4*)&hl[wid][2][dq * 4];
            float4 h3 = *(const float4*)&hl[wid][3][dq * 4];
            float w0 = Wl[dq * 4 + 0][o];
            float w1 = Wl[dq * 4 + 1][o];
            float w2 = Wl[dq * 4 + 2][o];
            float w3 = Wl[dq * 4 + 3][o];
            a0 = fmaf(h0.w, w3, fmaf(h0.z, w2, fmaf(h0.y, w1, fmaf(h0.x, w0, a0))));
            a1 = fmaf(h1.w, w3, fmaf(h1.z, w2, fmaf(h1.y, w1, fmaf(h1.x, w0, a1))));
            a2 = fmaf(h2.w, w3, fmaf(h2.z, w2, fmaf(h2.y, w1, fmaf(h2.x, w0, a2))));
            a3 = fmaf(h3.w, w3, fmaf(h3.z, w2, fmaf(h3.y, w1, fmaf(h3.x, w0, a3))));
        }
        if (r0 + 0 < N_NODES) out[(long long)(r0 + 0) * D + o] = fmaxf(a0, 0.0f);
        if (r0 + 1 < N_NODES) out[(long long)(r0 + 1) * D + o] = fmaxf(a1, 0.0f);
        if (r0 + 2 < N_NODES) out[(long long)(r0 + 2) * D + o] = fmaxf(a2, 0.0f);
        if (r0 + 3 < N_NODES) out[(long long)(r0 + 3) * D + o] = fmaxf(a3, 0.0f);
    }
}

// ============ fallback path (fp32 atomic scatter, round-2 proven) ============

__global__ __launch_bounds__(256) void gine_init(const float* __restrict__ x,
                                                 const float* __restrict__ eps,
                                                 float* __restrict__ out, int n4) {
    int i = blockIdx.x * blockDim.x + threadIdx.x;
    float s = 1.0f + eps[0];
    if (i < n4) {
        float4 v = ((const float4*)x)[i];
        v.x *= s; v.y *= s; v.z *= s; v.w *= s;
        ((float4*)out)[i] = v;
    }
}

__global__ __launch_bounds__(256) void gine_edges(const float* __restrict__ x,
                                                  const int* __restrict__ ei,
                                                  const float* __restrict__ ea,
                                                  float* __restrict__ out) {
    int e = blockIdx.x * (blockDim.x >> 6) + (threadIdx.x >> 6);
    int d = threadIdx.x & 63;
    if (e < N_EDGES) {
        int s = ei[e];
        int t = ei[N_EDGES + e];
        float m = fmaxf(x[(long long)s * D + d] + ea[(long long)e * D + d], 0.0f);
        atomicAdd(&out[(long long)t * D + d], m);
    }
}

__global__ __launch_bounds__(256) void gine_linear(float* __restrict__ h,
                                                   const float* __restrict__ W,
                                                   const float* __restrict__ b) {
    __shared__ float Wl[D][D + 1];
    __shared__ float bl[D];
    int tid = threadIdx.x;
    for (int i = tid; i < D * D; i += 256) Wl[i >> 6][i & 63] = W[i];
    if (tid < D) bl[tid] = b[tid];
    __syncthreads();
    int o = tid & 63;
    int row = blockIdx.x * 4 + (tid >> 6);
    if (row < N_NODES) {
        const float* hr = h + (long long)row * D;
        float acc = bl[o];
        #pragma unroll
        for (int d = 0; d < D; ++d) acc = fmaf(hr[d], Wl[o][d], acc);
        h[(long long)row * D + o] = fmaxf(acc, 0.0f);
    }
}

extern "C" void kernel_launch(void* const* d_in, const int* in_sizes, int n_in,
                              void* d_out, int out_size, void* d_ws, size_t ws_size,
                              hipStream_t stream) {
    const float* x   = (const float*)d_in[0];
    const int*   ei  = (const int*)d_in[1];   // int32 on device (harness narrows int64)
    const float* ea  = (const float*)d_in[2];
    const float* W   = (const float*)d_in[3];
    const float* b   = (const float*)d_in[4];
    const float* eps = (const float*)d_in[5];
    float* out = (float*)d_out;

    // ws layout: xh[N*D] bf16 | outb[N*D] bf16
    size_t need = (size_t)N_NODES * D * 2 * 2;
    if (ws_size >= need) {
        unsigned short* xh   = (unsigned short*)d_ws;
        unsigned short* outb = xh + (size_t)N_NODES * D;

        gine_prep<<<(N_NODES * D / 8 + 255) / 256, 256, 0, stream>>>(
            x, eps, (uint4*)xh, (uint4*)outb);
        gine_edges_pk<<<(N_EDGES * 32) / 256, 256, 0, stream>>>(xh, ei, ea, outb);
        gine_lin<<<(N_NODES + 63) / 64, 256, 0, stream>>>(outb, W, b, out);
    } else {
        int n4 = (N_NODES * D) / 4;
        gine_init<<<(n4 + 255) / 256, 256, 0, stream>>>(x, eps, out, n4);
        gine_edges<<<(N_EDGES + 3) / 4, 256, 0, stream>>>(x, ei, ea, out);
        gine_linear<<<(N_NODES + 3) / 4, 256, 0, stream>>>(out, W, b);
    }
}

// Round 13
// 212.367 us; speedup vs baseline: 6.3245x; 1.1571x over previous
//
#include <hip/hip_runtime.h>

#define N_NODES 100000
#define N_EDGES 1000000
#define D 64
#define EPK_BLOCKS 2048   // grid-stride: avoid CP dispatch-rate limit (G11)

typedef float f2v __attribute__((ext_vector_type(2)));

__device__ __forceinline__ unsigned int bf16_rne(float f) {
    unsigned int b = __float_as_uint(f);
    return (b + 0x7FFFu + ((b >> 16) & 1u)) >> 16;
}
__device__ __forceinline__ float bf16_lo(unsigned int v) { return __uint_as_float(v << 16); }
__device__ __forceinline__ float bf16_hi(unsigned int v) { return __uint_as_float(v & 0xFFFF0000u); }
__device__ __forceinline__ float bf16_f(unsigned short u) {
    return __uint_as_float(((unsigned int)u) << 16);
}

// prep: xh = bf16(x); ob = bf16((1+eps)*x)  (GIN base folded into the agg buffer).
__global__ __launch_bounds__(256) void gine_prep(const float* __restrict__ x,
                                                 const float* __restrict__ eps,
                                                 uint4* __restrict__ xh4,
                                                 uint4* __restrict__ ob4) {
    int i = blockIdx.x * 256 + threadIdx.x;
    float s = 1.0f + eps[0];
    if (i < N_NODES * D / 8) {
        float4 q0 = ((const float4*)x)[i * 2 + 0];
        float4 q1 = ((const float4*)x)[i * 2 + 1];
        uint4 a;
        a.x = bf16_rne(q0.x) | (bf16_rne(q0.y) << 16);
        a.y = bf16_rne(q0.z) | (bf16_rne(q0.w) << 16);
        a.z = bf16_rne(q1.x) | (bf16_rne(q1.y) << 16);
        a.w = bf16_rne(q1.z) | (bf16_rne(q1.w) << 16);
        xh4[i] = a;
        uint4 o;
        o.x = bf16_rne(s * q0.x) | (bf16_rne(s * q0.y) << 16);
        o.y = bf16_rne(s * q0.z) | (bf16_rne(s * q0.w) << 16);
        o.z = bf16_rne(s * q1.x) | (bf16_rne(s * q1.y) << 16);
        o.w = bf16_rne(s * q1.z) | (bf16_rne(s * q1.w) << 16);
        ob4[i] = o;
    }
}

// Streaming edge scatter, packed-bf16 atomics, GRID-STRIDE persistent form.
// One edge per 32-lane half-wave; lane covers feature pair (2*s2, 2*s2+1).
// Dense bursts (no skip): HW line-coalesces each edge's 32x4B same-row atomics.
__global__ __launch_bounds__(256) void gine_edges_pk(const unsigned short* __restrict__ xh,
                                                     const int* __restrict__ ei,
                                                     const float* __restrict__ ea,
                                                     unsigned short* __restrict__ outb) {
    const long long TOT = (long long)N_EDGES * 32;
    long long stride = (long long)gridDim.x * 256;     // multiple of 32
    long long t0 = (long long)blockIdx.x * 256 + threadIdx.x;
    int s2 = (int)(t0 & 31);                           // invariant across iterations
    for (long long task = t0; task < TOT; task += stride) {
        int w = (int)(task >> 5);      // edge index (uniform per half-wave)
        int src = ei[w];               // broadcast load (same addr across half-wave)
        int dst = ei[N_EDGES + w];
        f2v ev = __builtin_nontemporal_load((const f2v*)(ea + (long long)w * D) + s2);
        unsigned int xv = *((const unsigned int*)(xh + (long long)src * D) + s2);
        float mx = fmaxf(ev.x + bf16_lo(xv), 0.0f);
        float my = fmaxf(ev.y + bf16_hi(xv), 0.0f);
        unsigned int pk = bf16_rne(mx) | (bf16_rne(my) << 16);
        void* addr = (void*)(outb + (long long)dst * D + 2 * s2);
        asm volatile("global_atomic_pk_add_bf16 %0, %1, off" :: "v"(addr), "v"(pk) : "memory");
    }
    // no trailing drain: dispatch completion orders the atomics for the next kernel
}

// lin: out = relu(ob @ W^T + b); ob already holds (1+eps)x + aggregate.
__global__ __launch_bounds__(256) void gine_lin(const unsigned short* __restrict__ outb,
                                                const float* __restrict__ W,
                                                const float* __restrict__ bias,
                                                float* __restrict__ out) {
    __shared__ float Wl[D][D + 1];             // Wl[dd][o] = W[o][dd]
    __shared__ __align__(16) float hl[4][4][D];
    int tid = threadIdx.x;
    for (int i = tid; i < D * D; i += 256) {
        int o = i >> 6, dd = i & 63;
        Wl[dd][o] = W[i];
    }
    __syncthreads();

    int o = tid & 63;
    int wid = __builtin_amdgcn_readfirstlane(threadIdx.x >> 6);
    float bv = bias[o];
    int base = blockIdx.x * 64 + wid * 16;

    for (int t = 0; t < 4; ++t) {
        int r0 = base + t * 4;
        #pragma unroll
        for (int r = 0; r < 4; ++r) {
            int rr = r0 + r;
            float hv = 0.0f;
            if (rr < N_NODES) hv = bf16_f(outb[(long long)rr * D + o]);
            hl[wid][r][o] = hv;                // wave-private: no barrier needed
        }
        float a0 = bv, a1 = bv, a2 = bv, a3 = bv;
        #pragma unroll
        for (int dq = 0; dq < 16; ++dq) {
            float4 h0 = *(const float4*)&hl[wid][0][dq * 4];
            float4 h1 = *(const float4*)&hl[wid][1][dq * 4];
            float4 h2 = *(const float4*)&hl[wid][2][dq * 4];
            float4 h3 = *(const float4*)&hl[wid][3][dq * 4];
            float w0 = Wl[dq * 4 + 0][o];
            float w1 = Wl[dq * 4 + 1][o];
            float w2 = Wl[dq * 4 + 2][o];
            float w3 = Wl[dq * 4 + 3][o];
            a0 = fmaf(h0.w, w3, fmaf(h0.z, w2, fmaf(h0.y, w1, fmaf(h0.x, w0, a0))));
            a1 = fmaf(h1.w, w3, fmaf(h1.z, w2, fmaf(h1.y, w1, fmaf(h1.x, w0, a1))));
            a2 = fmaf(h2.w, w3, fmaf(h2.z, w2, fmaf(h2.y, w1, fmaf(h2.x, w0, a2))));
            a3 = fmaf(h3.w, w3, fmaf(h3.z, w2, fmaf(h3.y, w1, fmaf(h3.x, w0, a3))));
        }
        if (r0 + 0 < N_NODES) out[(long long)(r0 + 0) * D + o] = fmaxf(a0, 0.0f);
        if (r0 + 1 < N_NODES) out[(long long)(r0 + 1) * D + o] = fmaxf(a1, 0.0f);
        if (r0 + 2 < N_NODES) out[(long long)(r0 + 2) * D + o] = fmaxf(a2, 0.0f);
        if (r0 + 3 < N_NODES) out[(long long)(r0 + 3) * D + o] = fmaxf(a3, 0.0f);
    }
}

// ============ fallback path (fp32 atomic scatter, round-2 proven) ============

__global__ __launch_bounds__(256) void gine_init(const float* __restrict__ x,
                                                 const float* __restrict__ eps,
                                                 float* __restrict__ out, int n4) {
    int i = blockIdx.x * blockDim.x + threadIdx.x;
    float s = 1.0f + eps[0];
    if (i < n4) {
        float4 v = ((const float4*)x)[i];
        v.x *= s; v.y *= s; v.z *= s; v.w *= s;
        ((float4*)out)[i] = v;
    }
}

__global__ __launch_bounds__(256) void gine_edges(const float* __restrict__ x,
                                                  const int* __restrict__ ei,
                                                  const float* __restrict__ ea,
                                                  float* __restrict__ out) {
    int e = blockIdx.x * (blockDim.x >> 6) + (threadIdx.x >> 6);
    int d = threadIdx.x & 63;
    if (e < N_EDGES) {
        int s = ei[e];
        int t = ei[N_EDGES + e];
        float m = fmaxf(x[(long long)s * D + d] + ea[(long long)e * D + d], 0.0f);
        atomicAdd(&out[(long long)t * D + d], m);
    }
}

__global__ __launch_bounds__(256) void gine_linear(float* __restrict__ h,
                                                   const float* __restrict__ W,
                                                   const float* __restrict__ b) {
    __shared__ float Wl[D][D + 1];
    __shared__ float bl[D];
    int tid = threadIdx.x;
    for (int i = tid; i < D * D; i += 256) Wl[i >> 6][i & 63] = W[i];
    if (tid < D) bl[tid] = b[tid];
    __syncthreads();
    int o = tid & 63;
    int row = blockIdx.x * 4 + (tid >> 6);
    if (row < N_NODES) {
        const float* hr = h + (long long)row * D;
        float acc = bl[o];
        #pragma unroll
        for (int d = 0; d < D; ++d) acc = fmaf(hr[d], Wl[o][d], acc);
        h[(long long)row * D + o] = fmaxf(acc, 0.0f);
    }
}

extern "C" void kernel_launch(void* const* d_in, const int* in_sizes, int n_in,
                              void* d_out, int out_size, void* d_ws, size_t ws_size,
                              hipStream_t stream) {
    const float* x   = (const float*)d_in[0];
    const int*   ei  = (const int*)d_in[1];   // int32 on device (harness narrows int64)
    const float* ea  = (const float*)d_in[2];
    const float* W   = (const float*)d_in[3];
    const float* b   = (const float*)d_in[4];
    const float* eps = (const float*)d_in[5];
    float* out = (float*)d_out;

    // ws layout: xh[N*D] bf16 | outb[N*D] bf16
    size_t need = (size_t)N_NODES * D * 2 * 2;
    if (ws_size >= need) {
        unsigned short* xh   = (unsigned short*)d_ws;
        unsigned short* outb = xh + (size_t)N_NODES * D;

        gine_prep<<<(N_NODES * D / 8 + 255) / 256, 256, 0, stream>>>(
            x, eps, (uint4*)xh, (uint4*)outb);
        gine_edges_pk<<<EPK_BLOCKS, 256, 0, stream>>>(xh, ei, ea, outb);
        gine_lin<<<(N_NODES + 63) / 64, 256, 0, stream>>>(outb, W, b, out);
    } else {
        int n4 = (N_NODES * D) / 4;
        gine_init<<<(n4 + 255) / 256, 256, 0, stream>>>(x, eps, out, n4);
        gine_edges<<<(N_EDGES + 3) / 4, 256, 0, stream>>>(x, ei, ea, out);
        gine_linear<<<(N_NODES + 3) / 4, 256, 0, stream>>>(out, W, b);
    }
}